// Round 14
// baseline (537.785 us; speedup 1.0000x reference)
//
#include <hip/hip_runtime.h>
#include <stdint.h>

#define AS1 __attribute__((address_space(1)))
#define AS3 __attribute__((address_space(3)))

typedef __bf16 bf16x8 __attribute__((ext_vector_type(8)));
typedef float f32x4 __attribute__((ext_vector_type(4)));
typedef float f32x2 __attribute__((ext_vector_type(2)));

__device__ __forceinline__ float bf2f(unsigned short u) {
    return __uint_as_float(((unsigned)u) << 16);
}
__device__ __forceinline__ unsigned short f2bf(float f) {
    unsigned u = __float_as_uint(f);
    unsigned r = u + 0x7fffu + ((u >> 16) & 1u);  // RNE
    return (unsigned short)(r >> 16);
}
__device__ __forceinline__ void unpack4(uint2 u, float& a, float& b, float& c, float& d) {
    a = __uint_as_float(u.x << 16);
    b = __uint_as_float(u.x & 0xffff0000u);
    c = __uint_as_float(u.y << 16);
    d = __uint_as_float(u.y & 0xffff0000u);
}
__device__ __forceinline__ uint2 pack4(float a, float b, float c, float d) {
    uint2 o;
    o.x = (unsigned)f2bf(a) | ((unsigned)f2bf(b) << 16);
    o.y = (unsigned)f2bf(c) | ((unsigned)f2bf(d) << 16);
    return o;
}

// ---------------- prep: cwT transpose | zero pad rows | wfuse, one packed grid ----------------

__global__ void prep_kernel(const float* __restrict__ cw, unsigned short* __restrict__ cwT,
                            unsigned char* __restrict__ hz8, unsigned short* __restrict__ xz,
                            const float* __restrict__ nw, const float* __restrict__ nb,
                            unsigned short* __restrict__ w96) {
    __shared__ float colv[256];
    int b = blockIdx.x, t = threadIdx.x;
    if (b < 768) {
        int idx = b * 256 + t;  // over 3*256*256
        int l = idx >> 16, rem = idx & 65535;
        int k = rem >> 8, n = rem & 255;
        cwT[(l << 16) + (n << 8) + k] = f2bf(cw[idx]);
    } else if (b == 768) {
        hz8[t] = 0;
        if (t < 64) xz[t] = 0;
    } else {
        // W96T[n][k]: k<64 -> (node_w @ conv_w0)[k,n]; k==64 -> (node_b @ conv_w0)[n]; else 0
        int n = b - 769;
        colv[t] = cw[t * 256 + n];  // conv_w layer 0 column n
        __syncthreads();
        if (t < 64) {
            float acc = 0.0f;
            for (int j = 0; j < 256; j++) acc += nw[t * 256 + j] * colv[j];
            w96[n * 96 + t] = f2bf(acc);
        } else if (t == 64) {
            float acc = 0.0f;
            for (int j = 0; j < 256; j++) acc += nb[j] * colv[j];
            w96[n * 96 + t] = f2bf(acc);
        } else if (t < 96) {
            w96[n * 96 + t] = 0;
        }
    }
}

// ---------------- degree / CSR build ----------------

__global__ void deg_kernel(const int* __restrict__ col, int* __restrict__ cnt, int E) {
    int e = blockIdx.x * 256 + threadIdx.x;
    if (e < E) atomicAdd(&cnt[col[e]], 1);
}

__global__ void scan1_kernel(const int* __restrict__ cnt, int* __restrict__ scanbuf,
                             int* __restrict__ bsum, float* __restrict__ dis, int N) {
    __shared__ int s[512];
    int i = blockIdx.x * 512 + threadIdx.x;
    int c = (i < N) ? cnt[i] : 0;
    if (i < N) dis[i] = rsqrtf((float)c + 1.0f);  // +1 self-loop
    s[threadIdx.x] = c;
    __syncthreads();
    for (int off = 1; off < 512; off <<= 1) {
        int t = (threadIdx.x >= off) ? s[threadIdx.x - off] : 0;
        __syncthreads();
        s[threadIdx.x] += t;
        __syncthreads();
    }
    if (i < N) scanbuf[i] = s[threadIdx.x];
    if (threadIdx.x == 511) bsum[blockIdx.x] = s[511];
}

__global__ void scan2_kernel(const int* __restrict__ bsum, int* __restrict__ boff, int nb) {
    __shared__ int s[128];
    int t = threadIdx.x;
    int v = (t < nb) ? bsum[t] : 0;
    s[t] = v;
    __syncthreads();
    for (int off = 1; off < 128; off <<= 1) {
        int u = (t >= off) ? s[t - off] : 0;
        __syncthreads();
        s[t] += u;
        __syncthreads();
    }
    if (t < nb) boff[t] = s[t] - v;  // exclusive
}

__global__ void scan3_kernel(const int* __restrict__ scanbuf, const int* __restrict__ boff,
                             int* __restrict__ rowstart, int N) {
    int i = blockIdx.x * 256 + threadIdx.x;
    if (i < N) rowstart[i + 1] = scanbuf[i] + boff[i >> 9];
    if (i == 0) rowstart[0] = 0;
}

// scatter edges into CSR (atomicSub on warm cnt); also sdis[v] = sum dis[src]
__global__ void scatter_kernel(const int* __restrict__ row, const int* __restrict__ col,
                               const int* __restrict__ rowstart, int* __restrict__ cnt,
                               int* __restrict__ eidx, const float* __restrict__ dis,
                               float* __restrict__ sdis, int E) {
    int e = blockIdx.x * 256 + threadIdx.x;
    if (e < E) {
        int c = col[e];
        int r = row[e];
        int old = atomicSub(&cnt[c], 1);
        eidx[rowstart[c] + old - 1] = r;
        atomicAdd(&sdis[c], dis[r]);
    }
}

// xs[u] = dis[u] * x[u]  (bf16, N x 64)
__global__ void xs_kernel(const float* __restrict__ x, const float* __restrict__ dis,
                          unsigned short* __restrict__ xs, int total4) {
    int i4 = blockIdx.x * 256 + threadIdx.x;
    if (i4 < total4) {
        int i = i4 * 4;
        float d = dis[i >> 6];
        float4 v = *reinterpret_cast<const float4*>(x + i);
        *reinterpret_cast<uint2*>(xs + i) = pack4(d * v.x, d * v.y, d * v.z, d * v.w);
    }
}

// ---------------- GEMM (m97 recipe): C[M,Nc] = A[M,K] * BT[Nc,K]^T ----------------
// bf16 in, fp32 MFMA accumulate; out bf16 (C) OR fp8 e4m3 (C8);
// optional per-row scale[mr]; stats_accum (layer-1 BN); stats_clear for next agg.

__global__ __launch_bounds__(256)
void gemm_bt_kernel(const unsigned short* __restrict__ A, const unsigned short* __restrict__ BT,
                    unsigned short* __restrict__ C, unsigned char* __restrict__ C8,
                    const float* __restrict__ scale,
                    float* __restrict__ stats_accum, float* __restrict__ stats_clear,
                    int M, int K, int Nc) {
    __shared__ unsigned short As[128 * 32];
    __shared__ unsigned short Bs[128 * 32];
    __shared__ float stLS[256];

    if (stats_clear && blockIdx.x == 0 && blockIdx.y == 0) {
        stats_clear[threadIdx.x] = 0.0f;
        stats_clear[256 + threadIdx.x] = 0.0f;
    }
    if (stats_accum) stLS[threadIdx.x] = 0.0f;

    const int lane = threadIdx.x & 63;
    const int wave = threadIdx.x >> 6;
    const int wm = wave >> 1, wn = wave & 1;
    const int r = lane & 15, q = lane >> 4;
    const int m0b = blockIdx.x * 128;
    const int n0b = blockIdx.y * 128;
    const int m0 = m0b + wm * 64;
    const int n0 = n0b + wn * 64;

    f32x4 acc[4][4] = {};

    for (int k0 = 0; k0 < K; k0 += 32) {
        __syncthreads();  // previous tile consumed
#pragma unroll
        for (int j = 0; j < 2; j++) {
            int s = threadIdx.x + j * 256;        // 512 slots of 16 B
            int row = s >> 2, kp = s & 3;
            int mr = m0b + row;
            if (mr >= M) mr = M - 1;
            const unsigned short* ga = A + (size_t)mr * K + k0 + kp * 8;
            __builtin_amdgcn_global_load_lds((const AS1 void*)ga, (AS3 void*)(As + s * 8), 16, 0, 0);
            int nr = n0b + row;                    // Nc is a multiple of 128
            const unsigned short* gb = BT + (size_t)nr * K + k0 + kp * 8;
            __builtin_amdgcn_global_load_lds((const AS1 void*)gb, (AS3 void*)(Bs + s * 8), 16, 0, 0);
        }
        __syncthreads();  // drains vmcnt -> LDS ready

        bf16x8 a[4], b[4];
#pragma unroll
        for (int i = 0; i < 4; i++)
            a[i] = *reinterpret_cast<const bf16x8*>(As + ((wm * 64 + i * 16 + r) * 32 + q * 8));
#pragma unroll
        for (int j = 0; j < 4; j++)
            b[j] = *reinterpret_cast<const bf16x8*>(Bs + ((wn * 64 + j * 16 + r) * 32 + q * 8));
#pragma unroll
        for (int i = 0; i < 4; i++)
#pragma unroll
            for (int j = 0; j < 4; j++)
                acc[i][j] = __builtin_amdgcn_mfma_f32_16x16x32_bf16(a[i], b[j], acc[i][j], 0, 0, 0);
    }

    float psl[4] = {}, pql[4] = {};
#pragma unroll
    for (int i = 0; i < 4; i++) {
#pragma unroll
        for (int t = 0; t < 4; t++) {
            int mr = m0 + i * 16 + q * 4 + t;  // C/D: row = q*4+reg, col = lane&15
            if (mr < M) {
                float rs = scale ? scale[mr] : 1.0f;
#pragma unroll
                for (int j = 0; j < 4; j++) {
                    int nc = n0 + j * 16 + r;
                    float v = acc[i][j][t] * rs;
                    if (C8) {
                        int pk = __builtin_amdgcn_cvt_pk_fp8_f32(v, v, 0, false);
                        C8[(size_t)mr * Nc + nc] = (unsigned char)(pk & 0xFF);
                    } else {
                        C[(size_t)mr * Nc + nc] = f2bf(v);
                    }
                    psl[j] += v;
                    pql[j] += v * v;
                }
            }
        }
    }

    if (stats_accum) {
        __syncthreads();  // stLS zeroed by all threads
#pragma unroll
        for (int j = 0; j < 4; j++) {
            int c = wn * 64 + j * 16 + r;
            atomicAdd(&stLS[c], psl[j]);
            atomicAdd(&stLS[128 + c], pql[j]);
        }
        __syncthreads();
        if (threadIdx.x < 128) {
            atomicAdd(&stats_accum[n0b + threadIdx.x], stLS[threadIdx.x]);
            atomicAdd(&stats_accum[256 + n0b + threadIdx.x], stLS[128 + threadIdx.x]);
        }
    }
}

// ---------------- aggx: layer-1 aggregation over xs (64 feats) -> y96 ----------------

__global__ __launch_bounds__(256)
void aggx_kernel(const unsigned short* __restrict__ xs, const int* __restrict__ rowstart,
                 const int* __restrict__ eidx, const float* __restrict__ dis,
                 const float* __restrict__ sdis, unsigned short* __restrict__ y96, int N) {
    const int lane = threadIdx.x & 63;
    const int wave = threadIdx.x >> 6;
    const int slot = lane >> 3;       // 8 edges per round
    const int fl = (lane & 7) * 8;    // 8 features per lane

    const int vb = __builtin_amdgcn_readfirstlane(blockIdx.x * 16 + wave * 4);

    int rs[5];
#pragma unroll
    for (int s = 0; s < 5; s++) rs[s] = rowstart[min(vb + s, N)];
    int js[4], de[4];
    float dvv[4], svv[4];
#pragma unroll
    for (int s = 0; s < 4; s++) {
        js[s] = rs[s];
        bool ok = (vb + s) < N;
        de[s] = ok ? (rs[s + 1] - rs[s]) : 0;
        float dv = ok ? dis[vb + s] : 0.0f;
        dvv[s] = dv;
        svv[s] = ok ? (dv * (dv + sdis[vb + s])) : 0.0f;
    }

    int idx0 = (lane < de[0]) ? eidx[js[0] + lane] : N;
    int idx1 = (lane < de[1]) ? eidx[js[1] + lane] : N;
    int idx2 = (lane < de[2]) ? eidx[js[2] + lane] : N;
    int idx3 = (lane < de[3]) ? eidx[js[3] + lane] : N;

    uint4 sf[4];
#pragma unroll
    for (int s = 0; s < 4; s++)
        sf[s] = *reinterpret_cast<const uint4*>(xs + (size_t)min(vb + s, N) * 64 + fl);

    uint4 rA[2], rB[2], rC[2];

    auto issue = [&](int myidx, uint4 (&rr)[2]) {
#pragma unroll
        for (int ro = 0; ro < 2; ro++) {
            int u = __shfl(myidx, ro * 8 + slot);
            rr[ro] = *reinterpret_cast<const uint4*>(xs + (size_t)u * 64 + fl);
        }
    };

    auto consume = [&](int s, int js_s, int d, float dv, float sv, int myidx, uint4 (&rr)[2]) {
        float a[8] = {};
#pragma unroll
        for (int ro = 0; ro < 2; ro++) {
            float x0, x1, x2, x3;
            unpack4(make_uint2(rr[ro].x, rr[ro].y), x0, x1, x2, x3);
            a[0] += x0; a[1] += x1; a[2] += x2; a[3] += x3;
            unpack4(make_uint2(rr[ro].z, rr[ro].w), x0, x1, x2, x3);
            a[4] += x0; a[5] += x1; a[6] += x2; a[7] += x3;
        }
        int cnp = min(64, (d + 15) & ~15);
        for (int t = 16; t < cnp; t += 16) {
#pragma unroll
            for (int ro = 0; ro < 2; ro++) {
                int u = __shfl(myidx, t + ro * 8 + slot);
                rr[ro] = *reinterpret_cast<const uint4*>(xs + (size_t)u * 64 + fl);
            }
#pragma unroll
            for (int ro = 0; ro < 2; ro++) {
                float x0, x1, x2, x3;
                unpack4(make_uint2(rr[ro].x, rr[ro].y), x0, x1, x2, x3);
                a[0] += x0; a[1] += x1; a[2] += x2; a[3] += x3;
                unpack4(make_uint2(rr[ro].z, rr[ro].w), x0, x1, x2, x3);
                a[4] += x0; a[5] += x1; a[6] += x2; a[7] += x3;
            }
        }
        for (int base = 64; base < d; base += 64) {
            int mi = (base + lane < d) ? eidx[js_s + base + lane] : N;
            int cn2 = min(64, d - base);
            int cnp2 = (cn2 + 15) & ~15;
            for (int t = 0; t < cnp2; t += 16) {
#pragma unroll
                for (int ro = 0; ro < 2; ro++) {
                    int u = __shfl(mi, t + ro * 8 + slot);
                    rr[ro] = *reinterpret_cast<const uint4*>(xs + (size_t)u * 64 + fl);
                }
#pragma unroll
                for (int ro = 0; ro < 2; ro++) {
                    float x0, x1, x2, x3;
                    unpack4(make_uint2(rr[ro].x, rr[ro].y), x0, x1, x2, x3);
                    a[0] += x0; a[1] += x1; a[2] += x2; a[3] += x3;
                    unpack4(make_uint2(rr[ro].z, rr[ro].w), x0, x1, x2, x3);
                    a[4] += x0; a[5] += x1; a[6] += x2; a[7] += x3;
                }
            }
        }
#pragma unroll
        for (int j = 0; j < 8; j++) {
            a[j] += __shfl_xor(a[j], 8);
            a[j] += __shfl_xor(a[j], 16);
            a[j] += __shfl_xor(a[j], 32);
        }
        if ((vb + s) < N) {
            if (lane < 8) {
                float x0, x1, x2, x3;
                unpack4(make_uint2(sf[s].x, sf[s].y), x0, x1, x2, x3);
                a[0] += x0; a[1] += x1; a[2] += x2; a[3] += x3;
                unpack4(make_uint2(sf[s].z, sf[s].w), x0, x1, x2, x3);
                a[4] += x0; a[5] += x1; a[6] += x2; a[7] += x3;
                uint2 lo = pack4(dv * a[0], dv * a[1], dv * a[2], dv * a[3]);
                uint2 hi = pack4(dv * a[4], dv * a[5], dv * a[6], dv * a[7]);
                *reinterpret_cast<uint4*>(y96 + (size_t)(vb + s) * 96 + fl) =
                    make_uint4(lo.x, lo.y, hi.x, hi.y);
            } else if (lane < 12) {
                unsigned sx = (lane == 8) ? (unsigned)f2bf(sv) : 0u;
                *reinterpret_cast<uint4*>(y96 + (size_t)(vb + s) * 96 + 64 + (lane - 8) * 8) =
                    make_uint4(sx, 0u, 0u, 0u);
            }
        }
    };

    issue(idx0, rA);
    issue(idx1, rB);
    issue(idx2, rC);
    consume(0, js[0], de[0], dvv[0], svv[0], idx0, rA);
    issue(idx3, rA);
    consume(1, js[1], de[1], dvv[1], svv[1], idx1, rB);
    consume(2, js[2], de[2], dvv[2], svv[2], idx2, rC);
    consume(3, js[3], de[3], dvv[3], svv[3], idx3, rA);
}

// ---------------- agg8: fp8 e4m3 gather aggregation (layers 2 & 3) + fused BN stats ----------------
// Row = 256 B; lane owns 16 feats (uint4); 4 edges per wave-load (sub = lane>>4).
// Double-buffered (depth proven neutral); BN stats accumulated in LDS per wave
// (each slot owned by exactly one lane -> no conflicts, no atomics).
// __launch_bounds__(256,5): cap 102 VGPR -> up to 5 blocks/CU (occupancy probe).

__global__ __launch_bounds__(256, 5)
void agg8_kernel(const unsigned char* __restrict__ hws8, const int* __restrict__ rowstart,
                 const int* __restrict__ eidx, const float* __restrict__ dis,
                 unsigned short* __restrict__ agg, float* __restrict__ stats, int N) {
    __shared__ float s_sum[4][256];
    __shared__ float s_sq[4][256];
    const int lane = threadIdx.x & 63;
    const int wave = threadIdx.x >> 6;
    const int sub = lane >> 4;          // 4 edges per wave-load
    const int fl = (lane & 15) * 16;    // 16 features per lane

    // zero this wave's stats rows (sub==0 lanes own all 256 feats)
    if (sub == 0) {
#pragma unroll
        for (int j = 0; j < 16; j++) {
            s_sum[wave][fl + j] = 0.0f;
            s_sq[wave][fl + j] = 0.0f;
        }
    }

    const int vb = __builtin_amdgcn_readfirstlane(blockIdx.x * 16 + wave * 4);

    int rs[5];
#pragma unroll
    for (int s = 0; s < 5; s++) rs[s] = rowstart[min(vb + s, N)];
    int js[4], de[4];
    float dvv[4];
#pragma unroll
    for (int s = 0; s < 4; s++) {
        js[s] = rs[s];
        de[s] = (vb + s < N) ? (rs[s + 1] - rs[s]) : 0;
        dvv[s] = (vb + s < N) ? dis[vb + s] : 0.0f;
    }

    int idx0 = (lane < de[0]) ? eidx[js[0] + lane] : N;
    int idx1 = (lane < de[1]) ? eidx[js[1] + lane] : N;
    int idx2 = (lane < de[2]) ? eidx[js[2] + lane] : N;
    int idx3 = (lane < de[3]) ? eidx[js[3] + lane] : N;
    uint4 sf[4];
#pragma unroll
    for (int s = 0; s < 4; s++)
        sf[s] = *reinterpret_cast<const uint4*>(hws8 + (size_t)min(vb + s, N) * 256 + fl);

    uint4 rA[4], rB[4];

    auto addrow = [&](uint4 v, float (&a)[16]) {
#pragma unroll
        for (int w = 0; w < 4; w++) {
            unsigned dw = (w == 0) ? v.x : (w == 1) ? v.y : (w == 2) ? v.z : v.w;
            f32x2 lo = __builtin_amdgcn_cvt_pk_f32_fp8(dw, false);
            f32x2 hi = __builtin_amdgcn_cvt_pk_f32_fp8(dw, true);
            a[w * 4 + 0] += lo.x; a[w * 4 + 1] += lo.y;
            a[w * 4 + 2] += hi.x; a[w * 4 + 3] += hi.y;
        }
    };

    auto issue = [&](int myidx, uint4 (&rr)[4]) {
#pragma unroll
        for (int k = 0; k < 4; k++) {
            int u = __shfl(myidx, 4 * k + sub);
            rr[k] = *reinterpret_cast<const uint4*>(hws8 + (size_t)u * 256 + fl);
        }
    };

    auto consume = [&](int s, int js_s, int d, float dvs, int myidx, uint4 (&rr)[4]) {
        float a[16] = {};
#pragma unroll
        for (int k = 0; k < 4; k++) addrow(rr[k], a);
        int cnp = min(64, (d + 15) & ~15);
        for (int t = 16; t < cnp; t += 16) {
#pragma unroll
            for (int k = 0; k < 4; k++) {
                int u = __shfl(myidx, t + 4 * k + sub);
                rr[k] = *reinterpret_cast<const uint4*>(hws8 + (size_t)u * 256 + fl);
            }
#pragma unroll
            for (int k = 0; k < 4; k++) addrow(rr[k], a);
        }
        for (int base = 64; base < d; base += 64) {
            int mi = (base + lane < d) ? eidx[js_s + base + lane] : N;
            int cn2 = min(64, d - base);
            int cnp2 = (cn2 + 15) & ~15;
            for (int t = 0; t < cnp2; t += 16) {
#pragma unroll
                for (int k = 0; k < 4; k++) {
                    int u = __shfl(mi, t + 4 * k + sub);
                    rr[k] = *reinterpret_cast<const uint4*>(hws8 + (size_t)u * 256 + fl);
                }
#pragma unroll
                for (int k = 0; k < 4; k++) addrow(rr[k], a);
            }
        }
        // reduce across the 4 edge slots (bits 4,5 of lane)
#pragma unroll
        for (int j = 0; j < 16; j++) {
            a[j] += __shfl_xor(a[j], 16);
            a[j] += __shfl_xor(a[j], 32);
        }
        addrow(sf[s], a);  // self
        if (vb + s < N && sub == 0) {
            float g[16];
#pragma unroll
            for (int j = 0; j < 16; j++) g[j] = dvs * a[j];
            uint2 p0 = pack4(g[0], g[1], g[2], g[3]);
            uint2 p1 = pack4(g[4], g[5], g[6], g[7]);
            uint2 p2 = pack4(g[8], g[9], g[10], g[11]);
            uint2 p3 = pack4(g[12], g[13], g[14], g[15]);
            *reinterpret_cast<uint4*>(agg + (size_t)(vb + s) * 256 + fl) =
                make_uint4(p0.x, p0.y, p1.x, p1.y);
            *reinterpret_cast<uint4*>(agg + (size_t)(vb + s) * 256 + fl + 8) =
                make_uint4(p2.x, p2.y, p3.x, p3.y);
#pragma unroll
            for (int j = 0; j < 16; j++) {
                s_sum[wave][fl + j] += g[j];
                s_sq[wave][fl + j] += g[j] * g[j];
            }
        }
    };

    issue(idx0, rA);
    issue(idx1, rB);
    consume(0, js[0], de[0], dvv[0], idx0, rA);
    issue(idx2, rA);
    consume(1, js[1], de[1], dvv[1], idx1, rB);
    issue(idx3, rB);
    consume(2, js[2], de[2], dvv[2], idx2, rA);
    consume(3, js[3], de[3], dvv[3], idx3, rB);

    __syncthreads();

    int f = threadIdx.x;
    float ts = s_sum[0][f] + s_sum[1][f] + s_sum[2][f] + s_sum[3][f];
    float tq = s_sq[0][f] + s_sq[1][f] + s_sq[2][f] + s_sq[3][f];
    atomicAdd(&stats[f], ts);
    atomicAdd(&stats[256 + f], tq);
}

// ---------------- elem: BN affine (inline from stats) + ReLU -> bf16 h (layers 1-2) ----------------

__global__ __launch_bounds__(256)
void elem_kernel(const unsigned short* __restrict__ agg, const float* __restrict__ stats,
                 const float* __restrict__ bng, const float* __restrict__ bnb,
                 unsigned short* __restrict__ h, float inv_n, size_t total) {
    __shared__ float ssL[512];
    {
        int f = threadIdx.x;
        float mean = stats[f] * inv_n;
        float var = stats[256 + f] * inv_n - mean * mean;
        float sc = bng[f] * rsqrtf(var + 1e-5f);
        ssL[f] = sc;
        ssL[256 + f] = bnb[f] - mean * sc;
    }
    __syncthreads();
    size_t i = ((size_t)blockIdx.x * 256 + threadIdx.x) * 4;
    if (i < total) {
        float a0, a1, a2, a3;
        unpack4(*reinterpret_cast<const uint2*>(agg + i), a0, a1, a2, a3);
        int f = (int)(i & 255);
        float r0 = fmaxf(a0 * ssL[f] + ssL[256 + f], 0.0f);
        float r1 = fmaxf(a1 * ssL[f + 1] + ssL[256 + f + 1], 0.0f);
        float r2 = fmaxf(a2 * ssL[f + 2] + ssL[256 + f + 2], 0.0f);
        float r3 = fmaxf(a3 * ssL[f + 3] + ssL[256 + f + 3], 0.0f);
        *reinterpret_cast<uint2*>(h + i) = pack4(r0, r1, r2, r3);
    }
}

// ---------------- elem_pool: layer-3 BN+ReLU fused directly into global_add_pool ----------------

__global__ __launch_bounds__(256)
void elem_pool_kernel(const unsigned short* __restrict__ agg, const float* __restrict__ stats,
                      const float* __restrict__ bng, const float* __restrict__ bnb,
                      const int* __restrict__ batch, float* __restrict__ g,
                      float inv_n, int N) {
    __shared__ float ssL[512];
    __shared__ int sb[32];
    int f = threadIdx.x;
    {
        float mean = stats[f] * inv_n;
        float var = stats[256 + f] * inv_n - mean * mean;
        float sc = bng[f] * rsqrtf(var + 1e-5f);
        ssL[f] = sc;
        ssL[256 + f] = bnb[f] - mean * sc;
    }
    int r0 = blockIdx.x * 32;
    int rows = min(32, N - r0);
    if (f < 32) sb[f] = (r0 + f < N) ? batch[r0 + f] : -1;
    __syncthreads();
    float sc = ssL[f], sh = ssL[256 + f];
    float acc = 0.0f;
    int cur = sb[0];
    for (int t = 0; t < rows; t++) {
        int b = sb[t];
        if (b != cur) {
            atomicAdd(&g[cur * 256 + f], acc);
            acc = 0.0f;
            cur = b;
        }
        float v = bf2f(agg[(size_t)(r0 + t) * 256 + f]);
        acc += fmaxf(v * sc + sh, 0.0f);
    }
    atomicAdd(&g[cur * 256 + f], acc);
}

// ---------------- head MLP: relu(g@w1+b1)@w2+b2 ----------------

__global__ void head_kernel(const float* __restrict__ g, const float* __restrict__ w1,
                            const float* __restrict__ b1, const float* __restrict__ w2,
                            const float* __restrict__ b2, float* __restrict__ out) {
    __shared__ float gr[256];
    __shared__ float z[128];
    int b = blockIdx.x, t = threadIdx.x;
    gr[t] = g[b * 256 + t];
    gr[t + 128] = g[b * 256 + 128 + t];
    __syncthreads();
    float acc = b1[t];
    for (int k = 0; k < 256; k++) acc += gr[k] * w1[k * 128 + t];
    z[t] = fmaxf(acc, 0.0f);
    __syncthreads();
    if (t < 12) {
        float o = b2[t];
        for (int k = 0; k < 128; k++) o += z[k] * w2[k * 12 + t];
        out[b * 12 + t] = o;
    }
}

// ---------------- launch ----------------

extern "C" void kernel_launch(void* const* d_in, const int* in_sizes, int n_in,
                              void* d_out, int out_size, void* d_ws, size_t ws_size,
                              hipStream_t stream) {
    const float* x      = (const float*)d_in[0];
    const int*   ei     = (const int*)d_in[1];
    const int*   batch  = (const int*)d_in[2];
    const float* node_w = (const float*)d_in[3];
    const float* node_b = (const float*)d_in[4];
    const float* conv_w = (const float*)d_in[5];
    const float* bn_g   = (const float*)d_in[7];
    const float* bn_b   = (const float*)d_in[8];
    const float* hw1    = (const float*)d_in[9];
    const float* hb1    = (const float*)d_in[10];
    const float* hw2    = (const float*)d_in[11];
    const float* hb2    = (const float*)d_in[12];
    float* out = (float*)d_out;

    const int N = in_sizes[2];
    const int E = in_sizes[1] / 2;
    const int H = 256;
    const float inv_n = 1.0f / (float)N;

    char* base = (char*)d_ws;
    size_t off = 0;
    auto alloc = [&](size_t bytes) -> void* {
        off = (off + 255) & ~(size_t)255;
        void* p = base + off;
        off += bytes;
        return p;
    };
    unsigned short* xs  = (unsigned short*)alloc((size_t)(N + 1) * 64 * 2);   // +1 zero row
    unsigned short* y96 = (unsigned short*)alloc((size_t)N * 96 * 2);
    unsigned short* w96 = (unsigned short*)alloc((size_t)256 * 96 * 2);
    unsigned short* h   = (unsigned short*)alloc((size_t)N * H * 2);
    unsigned char*  hws8 = (unsigned char*)alloc((size_t)(N + 1) * H);        // +1 zero row
    unsigned short* agg = (unsigned short*)alloc((size_t)N * H * 2);
    unsigned short* cwT = (unsigned short*)alloc((size_t)3 * H * H * 2);
    // contiguous zero region: cnt | sdis | stats | gpool
    int* zero_region = (int*)alloc(((size_t)2 * N + 512 + 64 * H) * 4);
    int* cnt      = zero_region;
    float* sdis   = (float*)(zero_region + N);
    float* stats  = (float*)(zero_region + 2 * N);
    float* gpool  = (float*)(zero_region + 2 * N + 512);
    int* rowstart = (int*)alloc((size_t)(N + 1) * 4);
    int* scanbuf  = (int*)alloc((size_t)N * 4);
    int* bsum     = (int*)alloc(1024);
    int* boff     = (int*)alloc(1024);
    int* eidx     = (int*)alloc((size_t)(E + 64) * 4);
    float* dis    = (float*)alloc((size_t)N * 4);

    const int* row = ei;
    const int* col = ei + E;

    hipMemsetAsync(zero_region, 0, ((size_t)2 * N + 512 + 64 * H) * 4, stream);

    // cwT transpose + zero pad rows + w96 fuse, one packed grid
    prep_kernel<<<dim3(768 + 1 + 256), 256, 0, stream>>>(
        conv_w, cwT, hws8 + (size_t)N * H, xs + (size_t)N * 64, node_w, node_b, w96);

    deg_kernel<<<dim3((E + 255) / 256), 256, 0, stream>>>(col, cnt, E);
    int nb = (N + 511) / 512;
    scan1_kernel<<<dim3(nb), 512, 0, stream>>>(cnt, scanbuf, bsum, dis, N);
    scan2_kernel<<<dim3(1), 128, 0, stream>>>(bsum, boff, nb);
    scan3_kernel<<<dim3((N + 255) / 256), 256, 0, stream>>>(scanbuf, boff, rowstart, N);
    scatter_kernel<<<dim3((E + 255) / 256), 256, 0, stream>>>(row, col, rowstart, cnt, eidx,
                                                              dis, sdis, E);
    xs_kernel<<<dim3((N * 64 / 4 + 255) / 256), 256, 0, stream>>>(x, dis, xs, N * 64 / 4);

    dim3 gg((N + 127) / 128, H / 128);
    size_t elem_blocks = ((size_t)N * H / 4 + 255) / 256;

    // layer 1: aggregate xs -> y96; K=96 GEMM with fused BN-stats accumulation
    aggx_kernel<<<dim3((N + 15) / 16), 256, 0, stream>>>(xs, rowstart, eidx, dis, sdis, y96, N);
    gemm_bt_kernel<<<gg, 256, 0, stream>>>(y96, w96, agg, nullptr, nullptr, stats, nullptr,
                                           N, 96, H);
    elem_kernel<<<dim3((int)elem_blocks), 256, 0, stream>>>(agg, stats, bn_g, bn_b, h,
                                                            inv_n, (size_t)N * H);

    // layer 2 (fp8 gather)
    gemm_bt_kernel<<<gg, 256, 0, stream>>>(h, cwT + (size_t)1 * H * H, nullptr, hws8, dis,
                                           nullptr, stats, N, H, H);
    agg8_kernel<<<dim3((N + 15) / 16), 256, 0, stream>>>(hws8, rowstart, eidx, dis, agg, stats, N);
    elem_kernel<<<dim3((int)elem_blocks), 256, 0, stream>>>(agg, stats, bn_g + H, bn_b + H, h,
                                                            inv_n, (size_t)N * H);

    // layer 3 (fp8 gather; elem fused into pool)
    gemm_bt_kernel<<<gg, 256, 0, stream>>>(h, cwT + (size_t)2 * H * H, nullptr, hws8, dis,
                                           nullptr, stats, N, H, H);
    agg8_kernel<<<dim3((N + 15) / 16), 256, 0, stream>>>(hws8, rowstart, eidx, dis, agg, stats, N);
    elem_pool_kernel<<<dim3((N + 31) / 32), 256, 0, stream>>>(agg, stats, bn_g + 2 * H,
                                                              bn_b + 2 * H, batch, gpool,
                                                              inv_n, N);

    head_kernel<<<dim3(64), 128, 0, stream>>>(gpool, hw1, hb1, hw2, hb2, out);
}

// Round 15
// 515.483 us; speedup vs baseline: 1.0433x; 1.0433x over previous
//
#include <hip/hip_runtime.h>
#include <stdint.h>

#define AS1 __attribute__((address_space(1)))
#define AS3 __attribute__((address_space(3)))

typedef __bf16 bf16x8 __attribute__((ext_vector_type(8)));
typedef float f32x4 __attribute__((ext_vector_type(4)));
typedef float f32x2 __attribute__((ext_vector_type(2)));

__device__ __forceinline__ float bf2f(unsigned short u) {
    return __uint_as_float(((unsigned)u) << 16);
}
__device__ __forceinline__ unsigned short f2bf(float f) {
    unsigned u = __float_as_uint(f);
    unsigned r = u + 0x7fffu + ((u >> 16) & 1u);  // RNE
    return (unsigned short)(r >> 16);
}
__device__ __forceinline__ void unpack4(uint2 u, float& a, float& b, float& c, float& d) {
    a = __uint_as_float(u.x << 16);
    b = __uint_as_float(u.x & 0xffff0000u);
    c = __uint_as_float(u.y << 16);
    d = __uint_as_float(u.y & 0xffff0000u);
}
__device__ __forceinline__ uint2 pack4(float a, float b, float c, float d) {
    uint2 o;
    o.x = (unsigned)f2bf(a) | ((unsigned)f2bf(b) << 16);
    o.y = (unsigned)f2bf(c) | ((unsigned)f2bf(d) << 16);
    return o;
}

// ---------------- prep: cwT transpose | zero pad rows | wfuse, one packed grid ----------------

__global__ void prep_kernel(const float* __restrict__ cw, unsigned short* __restrict__ cwT,
                            unsigned char* __restrict__ hz8, unsigned short* __restrict__ xz,
                            const float* __restrict__ nw, const float* __restrict__ nb,
                            unsigned short* __restrict__ w96) {
    __shared__ float colv[256];
    int b = blockIdx.x, t = threadIdx.x;
    if (b < 768) {
        int idx = b * 256 + t;  // over 3*256*256
        int l = idx >> 16, rem = idx & 65535;
        int k = rem >> 8, n = rem & 255;
        cwT[(l << 16) + (n << 8) + k] = f2bf(cw[idx]);
    } else if (b == 768) {
        hz8[t] = 0;
        if (t < 64) xz[t] = 0;
    } else {
        // W96T[n][k]: k<64 -> (node_w @ conv_w0)[k,n]; k==64 -> (node_b @ conv_w0)[n]; else 0
        int n = b - 769;
        colv[t] = cw[t * 256 + n];  // conv_w layer 0 column n
        __syncthreads();
        if (t < 64) {
            float acc = 0.0f;
            for (int j = 0; j < 256; j++) acc += nw[t * 256 + j] * colv[j];
            w96[n * 96 + t] = f2bf(acc);
        } else if (t == 64) {
            float acc = 0.0f;
            for (int j = 0; j < 256; j++) acc += nb[j] * colv[j];
            w96[n * 96 + t] = f2bf(acc);
        } else if (t < 96) {
            w96[n * 96 + t] = 0;
        }
    }
}

// ---------------- degree / CSR build ----------------

__global__ void deg_kernel(const int* __restrict__ col, int* __restrict__ cnt, int E) {
    int e = blockIdx.x * 256 + threadIdx.x;
    if (e < E) atomicAdd(&cnt[col[e]], 1);
}

__global__ void scan1_kernel(const int* __restrict__ cnt, int* __restrict__ scanbuf,
                             int* __restrict__ bsum, float* __restrict__ dis, int N) {
    __shared__ int s[512];
    int i = blockIdx.x * 512 + threadIdx.x;
    int c = (i < N) ? cnt[i] : 0;
    if (i < N) dis[i] = rsqrtf((float)c + 1.0f);  // +1 self-loop
    s[threadIdx.x] = c;
    __syncthreads();
    for (int off = 1; off < 512; off <<= 1) {
        int t = (threadIdx.x >= off) ? s[threadIdx.x - off] : 0;
        __syncthreads();
        s[threadIdx.x] += t;
        __syncthreads();
    }
    if (i < N) scanbuf[i] = s[threadIdx.x];
    if (threadIdx.x == 511) bsum[blockIdx.x] = s[511];
}

__global__ void scan2_kernel(const int* __restrict__ bsum, int* __restrict__ boff, int nb) {
    __shared__ int s[128];
    int t = threadIdx.x;
    int v = (t < nb) ? bsum[t] : 0;
    s[t] = v;
    __syncthreads();
    for (int off = 1; off < 128; off <<= 1) {
        int u = (t >= off) ? s[t - off] : 0;
        __syncthreads();
        s[t] += u;
        __syncthreads();
    }
    if (t < nb) boff[t] = s[t] - v;  // exclusive
}

__global__ void scan3_kernel(const int* __restrict__ scanbuf, const int* __restrict__ boff,
                             int* __restrict__ rowstart, int N) {
    int i = blockIdx.x * 256 + threadIdx.x;
    if (i < N) rowstart[i + 1] = scanbuf[i] + boff[i >> 9];
    if (i == 0) rowstart[0] = 0;
}

// scatter edges into CSR (atomicSub on warm cnt); also sdis[v] = sum dis[src]
__global__ void scatter_kernel(const int* __restrict__ row, const int* __restrict__ col,
                               const int* __restrict__ rowstart, int* __restrict__ cnt,
                               int* __restrict__ eidx, const float* __restrict__ dis,
                               float* __restrict__ sdis, int E) {
    int e = blockIdx.x * 256 + threadIdx.x;
    if (e < E) {
        int c = col[e];
        int r = row[e];
        int old = atomicSub(&cnt[c], 1);
        eidx[rowstart[c] + old - 1] = r;
        atomicAdd(&sdis[c], dis[r]);
    }
}

// xs[u] = dis[u] * x[u]  (bf16, N x 64)
__global__ void xs_kernel(const float* __restrict__ x, const float* __restrict__ dis,
                          unsigned short* __restrict__ xs, int total4) {
    int i4 = blockIdx.x * 256 + threadIdx.x;
    if (i4 < total4) {
        int i = i4 * 4;
        float d = dis[i >> 6];
        float4 v = *reinterpret_cast<const float4*>(x + i);
        *reinterpret_cast<uint2*>(xs + i) = pack4(d * v.x, d * v.y, d * v.z, d * v.w);
    }
}

// ---------------- GEMM (m97 recipe): C[M,Nc] = A[M,K] * BT[Nc,K]^T ----------------
// bf16 in, fp32 MFMA accumulate; out bf16 (C) OR fp8 e4m3 (C8);
// optional per-row scale[mr]; stats_accum (layer-1 BN); stats_clear for next agg.

__global__ __launch_bounds__(256)
void gemm_bt_kernel(const unsigned short* __restrict__ A, const unsigned short* __restrict__ BT,
                    unsigned short* __restrict__ C, unsigned char* __restrict__ C8,
                    const float* __restrict__ scale,
                    float* __restrict__ stats_accum, float* __restrict__ stats_clear,
                    int M, int K, int Nc) {
    __shared__ unsigned short As[128 * 32];
    __shared__ unsigned short Bs[128 * 32];
    __shared__ float stLS[256];

    if (stats_clear && blockIdx.x == 0 && blockIdx.y == 0) {
        stats_clear[threadIdx.x] = 0.0f;
        stats_clear[256 + threadIdx.x] = 0.0f;
    }
    if (stats_accum) stLS[threadIdx.x] = 0.0f;

    const int lane = threadIdx.x & 63;
    const int wave = threadIdx.x >> 6;
    const int wm = wave >> 1, wn = wave & 1;
    const int r = lane & 15, q = lane >> 4;
    const int m0b = blockIdx.x * 128;
    const int n0b = blockIdx.y * 128;
    const int m0 = m0b + wm * 64;
    const int n0 = n0b + wn * 64;

    f32x4 acc[4][4] = {};

    for (int k0 = 0; k0 < K; k0 += 32) {
        __syncthreads();  // previous tile consumed
#pragma unroll
        for (int j = 0; j < 2; j++) {
            int s = threadIdx.x + j * 256;        // 512 slots of 16 B
            int row = s >> 2, kp = s & 3;
            int mr = m0b + row;
            if (mr >= M) mr = M - 1;
            const unsigned short* ga = A + (size_t)mr * K + k0 + kp * 8;
            __builtin_amdgcn_global_load_lds((const AS1 void*)ga, (AS3 void*)(As + s * 8), 16, 0, 0);
            int nr = n0b + row;                    // Nc is a multiple of 128
            const unsigned short* gb = BT + (size_t)nr * K + k0 + kp * 8;
            __builtin_amdgcn_global_load_lds((const AS1 void*)gb, (AS3 void*)(Bs + s * 8), 16, 0, 0);
        }
        __syncthreads();  // drains vmcnt -> LDS ready

        bf16x8 a[4], b[4];
#pragma unroll
        for (int i = 0; i < 4; i++)
            a[i] = *reinterpret_cast<const bf16x8*>(As + ((wm * 64 + i * 16 + r) * 32 + q * 8));
#pragma unroll
        for (int j = 0; j < 4; j++)
            b[j] = *reinterpret_cast<const bf16x8*>(Bs + ((wn * 64 + j * 16 + r) * 32 + q * 8));
#pragma unroll
        for (int i = 0; i < 4; i++)
#pragma unroll
            for (int j = 0; j < 4; j++)
                acc[i][j] = __builtin_amdgcn_mfma_f32_16x16x32_bf16(a[i], b[j], acc[i][j], 0, 0, 0);
    }

    float psl[4] = {}, pql[4] = {};
#pragma unroll
    for (int i = 0; i < 4; i++) {
#pragma unroll
        for (int t = 0; t < 4; t++) {
            int mr = m0 + i * 16 + q * 4 + t;  // C/D: row = q*4+reg, col = lane&15
            if (mr < M) {
                float rs = scale ? scale[mr] : 1.0f;
#pragma unroll
                for (int j = 0; j < 4; j++) {
                    int nc = n0 + j * 16 + r;
                    float v = acc[i][j][t] * rs;
                    if (C8) {
                        int pk = __builtin_amdgcn_cvt_pk_fp8_f32(v, v, 0, false);
                        C8[(size_t)mr * Nc + nc] = (unsigned char)(pk & 0xFF);
                    } else {
                        C[(size_t)mr * Nc + nc] = f2bf(v);
                    }
                    psl[j] += v;
                    pql[j] += v * v;
                }
            }
        }
    }

    if (stats_accum) {
        __syncthreads();  // stLS zeroed by all threads
#pragma unroll
        for (int j = 0; j < 4; j++) {
            int c = wn * 64 + j * 16 + r;
            atomicAdd(&stLS[c], psl[j]);
            atomicAdd(&stLS[128 + c], pql[j]);
        }
        __syncthreads();
        if (threadIdx.x < 128) {
            atomicAdd(&stats_accum[n0b + threadIdx.x], stLS[threadIdx.x]);
            atomicAdd(&stats_accum[256 + n0b + threadIdx.x], stLS[128 + threadIdx.x]);
        }
    }
}

// ---------------- aggx: layer-1 aggregation over xs (64 feats) -> y96 ----------------

__global__ __launch_bounds__(256)
void aggx_kernel(const unsigned short* __restrict__ xs, const int* __restrict__ rowstart,
                 const int* __restrict__ eidx, const float* __restrict__ dis,
                 const float* __restrict__ sdis, unsigned short* __restrict__ y96, int N) {
    const int lane = threadIdx.x & 63;
    const int wave = threadIdx.x >> 6;
    const int slot = lane >> 3;       // 8 edges per round
    const int fl = (lane & 7) * 8;    // 8 features per lane

    const int vb = __builtin_amdgcn_readfirstlane(blockIdx.x * 16 + wave * 4);

    int rs[5];
#pragma unroll
    for (int s = 0; s < 5; s++) rs[s] = rowstart[min(vb + s, N)];
    int js[4], de[4];
    float dvv[4], svv[4];
#pragma unroll
    for (int s = 0; s < 4; s++) {
        js[s] = rs[s];
        bool ok = (vb + s) < N;
        de[s] = ok ? (rs[s + 1] - rs[s]) : 0;
        float dv = ok ? dis[vb + s] : 0.0f;
        dvv[s] = dv;
        svv[s] = ok ? (dv * (dv + sdis[vb + s])) : 0.0f;
    }

    int idx0 = (lane < de[0]) ? eidx[js[0] + lane] : N;
    int idx1 = (lane < de[1]) ? eidx[js[1] + lane] : N;
    int idx2 = (lane < de[2]) ? eidx[js[2] + lane] : N;
    int idx3 = (lane < de[3]) ? eidx[js[3] + lane] : N;

    uint4 sf[4];
#pragma unroll
    for (int s = 0; s < 4; s++)
        sf[s] = *reinterpret_cast<const uint4*>(xs + (size_t)min(vb + s, N) * 64 + fl);

    uint4 rA[2], rB[2], rC[2];

    auto issue = [&](int myidx, uint4 (&rr)[2]) {
#pragma unroll
        for (int ro = 0; ro < 2; ro++) {
            int u = __shfl(myidx, ro * 8 + slot);
            rr[ro] = *reinterpret_cast<const uint4*>(xs + (size_t)u * 64 + fl);
        }
    };

    auto consume = [&](int s, int js_s, int d, float dv, float sv, int myidx, uint4 (&rr)[2]) {
        float a[8] = {};
#pragma unroll
        for (int ro = 0; ro < 2; ro++) {
            float x0, x1, x2, x3;
            unpack4(make_uint2(rr[ro].x, rr[ro].y), x0, x1, x2, x3);
            a[0] += x0; a[1] += x1; a[2] += x2; a[3] += x3;
            unpack4(make_uint2(rr[ro].z, rr[ro].w), x0, x1, x2, x3);
            a[4] += x0; a[5] += x1; a[6] += x2; a[7] += x3;
        }
        int cnp = min(64, (d + 15) & ~15);
        for (int t = 16; t < cnp; t += 16) {
#pragma unroll
            for (int ro = 0; ro < 2; ro++) {
                int u = __shfl(myidx, t + ro * 8 + slot);
                rr[ro] = *reinterpret_cast<const uint4*>(xs + (size_t)u * 64 + fl);
            }
#pragma unroll
            for (int ro = 0; ro < 2; ro++) {
                float x0, x1, x2, x3;
                unpack4(make_uint2(rr[ro].x, rr[ro].y), x0, x1, x2, x3);
                a[0] += x0; a[1] += x1; a[2] += x2; a[3] += x3;
                unpack4(make_uint2(rr[ro].z, rr[ro].w), x0, x1, x2, x3);
                a[4] += x0; a[5] += x1; a[6] += x2; a[7] += x3;
            }
        }
        for (int base = 64; base < d; base += 64) {
            int mi = (base + lane < d) ? eidx[js_s + base + lane] : N;
            int cn2 = min(64, d - base);
            int cnp2 = (cn2 + 15) & ~15;
            for (int t = 0; t < cnp2; t += 16) {
#pragma unroll
                for (int ro = 0; ro < 2; ro++) {
                    int u = __shfl(mi, t + ro * 8 + slot);
                    rr[ro] = *reinterpret_cast<const uint4*>(xs + (size_t)u * 64 + fl);
                }
#pragma unroll
                for (int ro = 0; ro < 2; ro++) {
                    float x0, x1, x2, x3;
                    unpack4(make_uint2(rr[ro].x, rr[ro].y), x0, x1, x2, x3);
                    a[0] += x0; a[1] += x1; a[2] += x2; a[3] += x3;
                    unpack4(make_uint2(rr[ro].z, rr[ro].w), x0, x1, x2, x3);
                    a[4] += x0; a[5] += x1; a[6] += x2; a[7] += x3;
                }
            }
        }
#pragma unroll
        for (int j = 0; j < 8; j++) {
            a[j] += __shfl_xor(a[j], 8);
            a[j] += __shfl_xor(a[j], 16);
            a[j] += __shfl_xor(a[j], 32);
        }
        if ((vb + s) < N) {
            if (lane < 8) {
                float x0, x1, x2, x3;
                unpack4(make_uint2(sf[s].x, sf[s].y), x0, x1, x2, x3);
                a[0] += x0; a[1] += x1; a[2] += x2; a[3] += x3;
                unpack4(make_uint2(sf[s].z, sf[s].w), x0, x1, x2, x3);
                a[4] += x0; a[5] += x1; a[6] += x2; a[7] += x3;
                uint2 lo = pack4(dv * a[0], dv * a[1], dv * a[2], dv * a[3]);
                uint2 hi = pack4(dv * a[4], dv * a[5], dv * a[6], dv * a[7]);
                *reinterpret_cast<uint4*>(y96 + (size_t)(vb + s) * 96 + fl) =
                    make_uint4(lo.x, lo.y, hi.x, hi.y);
            } else if (lane < 12) {
                unsigned sx = (lane == 8) ? (unsigned)f2bf(sv) : 0u;
                *reinterpret_cast<uint4*>(y96 + (size_t)(vb + s) * 96 + 64 + (lane - 8) * 8) =
                    make_uint4(sx, 0u, 0u, 0u);
            }
        }
    };

    issue(idx0, rA);
    issue(idx1, rB);
    issue(idx2, rC);
    consume(0, js[0], de[0], dvv[0], svv[0], idx0, rA);
    issue(idx3, rA);
    consume(1, js[1], de[1], dvv[1], svv[1], idx1, rB);
    consume(2, js[2], de[2], dvv[2], svv[2], idx2, rC);
    consume(3, js[3], de[3], dvv[3], svv[3], idx3, rA);
}

// ---------------- agg8: fp8 e4m3 gather aggregation (layers 2 & 3) + fused BN stats ----------------
// R13-proven version: register ps/pq accumulators, plain launch bounds (no spill),
// double-buffered. Row = 256 B; lane owns 16 feats (uint4); 4 edges per wave-load.

__global__ __launch_bounds__(256)
void agg8_kernel(const unsigned char* __restrict__ hws8, const int* __restrict__ rowstart,
                 const int* __restrict__ eidx, const float* __restrict__ dis,
                 unsigned short* __restrict__ agg, float* __restrict__ stats, int N) {
    __shared__ float s_sum[4][256];
    __shared__ float s_sq[4][256];
    const int lane = threadIdx.x & 63;
    const int wave = threadIdx.x >> 6;
    const int sub = lane >> 4;          // 4 edges per wave-load
    const int fl = (lane & 15) * 16;    // 16 features per lane

    const int vb = __builtin_amdgcn_readfirstlane(blockIdx.x * 16 + wave * 4);

    int rs[5];
#pragma unroll
    for (int s = 0; s < 5; s++) rs[s] = rowstart[min(vb + s, N)];
    int js[4], de[4];
    float dvv[4];
#pragma unroll
    for (int s = 0; s < 4; s++) {
        js[s] = rs[s];
        de[s] = (vb + s < N) ? (rs[s + 1] - rs[s]) : 0;
        dvv[s] = (vb + s < N) ? dis[vb + s] : 0.0f;
    }

    int idx0 = (lane < de[0]) ? eidx[js[0] + lane] : N;
    int idx1 = (lane < de[1]) ? eidx[js[1] + lane] : N;
    int idx2 = (lane < de[2]) ? eidx[js[2] + lane] : N;
    int idx3 = (lane < de[3]) ? eidx[js[3] + lane] : N;
    uint4 sf[4];
#pragma unroll
    for (int s = 0; s < 4; s++)
        sf[s] = *reinterpret_cast<const uint4*>(hws8 + (size_t)min(vb + s, N) * 256 + fl);

    float ps[16] = {}, pq[16] = {};

    uint4 rA[4], rB[4];

    auto addrow = [&](uint4 v, float (&a)[16]) {
#pragma unroll
        for (int w = 0; w < 4; w++) {
            unsigned dw = (w == 0) ? v.x : (w == 1) ? v.y : (w == 2) ? v.z : v.w;
            f32x2 lo = __builtin_amdgcn_cvt_pk_f32_fp8(dw, false);
            f32x2 hi = __builtin_amdgcn_cvt_pk_f32_fp8(dw, true);
            a[w * 4 + 0] += lo.x; a[w * 4 + 1] += lo.y;
            a[w * 4 + 2] += hi.x; a[w * 4 + 3] += hi.y;
        }
    };

    auto issue = [&](int myidx, uint4 (&rr)[4]) {
#pragma unroll
        for (int k = 0; k < 4; k++) {
            int u = __shfl(myidx, 4 * k + sub);
            rr[k] = *reinterpret_cast<const uint4*>(hws8 + (size_t)u * 256 + fl);
        }
    };

    auto consume = [&](int s, int js_s, int d, float dvs, int myidx, uint4 (&rr)[4]) {
        float a[16] = {};
#pragma unroll
        for (int k = 0; k < 4; k++) addrow(rr[k], a);
        int cnp = min(64, (d + 15) & ~15);
        for (int t = 16; t < cnp; t += 16) {
#pragma unroll
            for (int k = 0; k < 4; k++) {
                int u = __shfl(myidx, t + 4 * k + sub);
                rr[k] = *reinterpret_cast<const uint4*>(hws8 + (size_t)u * 256 + fl);
            }
#pragma unroll
            for (int k = 0; k < 4; k++) addrow(rr[k], a);
        }
        for (int base = 64; base < d; base += 64) {
            int mi = (base + lane < d) ? eidx[js_s + base + lane] : N;
            int cn2 = min(64, d - base);
            int cnp2 = (cn2 + 15) & ~15;
            for (int t = 0; t < cnp2; t += 16) {
#pragma unroll
                for (int k = 0; k < 4; k++) {
                    int u = __shfl(mi, t + 4 * k + sub);
                    rr[k] = *reinterpret_cast<const uint4*>(hws8 + (size_t)u * 256 + fl);
                }
#pragma unroll
                for (int k = 0; k < 4; k++) addrow(rr[k], a);
            }
        }
        // reduce across the 4 edge slots (bits 4,5 of lane)
#pragma unroll
        for (int j = 0; j < 16; j++) {
            a[j] += __shfl_xor(a[j], 16);
            a[j] += __shfl_xor(a[j], 32);
        }
        addrow(sf[s], a);  // self
        float g[16];
#pragma unroll
        for (int j = 0; j < 16; j++) g[j] = dvs * a[j];
        if (vb + s < N && sub == 0) {
            uint2 p0 = pack4(g[0], g[1], g[2], g[3]);
            uint2 p1 = pack4(g[4], g[5], g[6], g[7]);
            uint2 p2 = pack4(g[8], g[9], g[10], g[11]);
            uint2 p3 = pack4(g[12], g[13], g[14], g[15]);
            *reinterpret_cast<uint4*>(agg + (size_t)(vb + s) * 256 + fl) =
                make_uint4(p0.x, p0.y, p1.x, p1.y);
            *reinterpret_cast<uint4*>(agg + (size_t)(vb + s) * 256 + fl + 8) =
                make_uint4(p2.x, p2.y, p3.x, p3.y);
#pragma unroll
            for (int j = 0; j < 16; j++) { ps[j] += g[j]; pq[j] += g[j] * g[j]; }
        }
    };

    issue(idx0, rA);
    issue(idx1, rB);
    consume(0, js[0], de[0], dvv[0], idx0, rA);
    issue(idx2, rA);
    consume(1, js[1], de[1], dvv[1], idx1, rB);
    issue(idx3, rB);
    consume(2, js[2], de[2], dvv[2], idx2, rA);
    consume(3, js[3], de[3], dvv[3], idx3, rB);

    if (sub == 0) {
#pragma unroll
        for (int j = 0; j < 16; j++) {
            s_sum[wave][fl + j] = ps[j];
            s_sq[wave][fl + j] = pq[j];
        }
    }
    __syncthreads();

    int f = threadIdx.x;
    float ts = s_sum[0][f] + s_sum[1][f] + s_sum[2][f] + s_sum[3][f];
    float tq = s_sq[0][f] + s_sq[1][f] + s_sq[2][f] + s_sq[3][f];
    atomicAdd(&stats[f], ts);
    atomicAdd(&stats[256 + f], tq);
}

// ---------------- elem: BN affine (inline from stats) + ReLU -> bf16 h (layers 1-2) ----------------

__global__ __launch_bounds__(256)
void elem_kernel(const unsigned short* __restrict__ agg, const float* __restrict__ stats,
                 const float* __restrict__ bng, const float* __restrict__ bnb,
                 unsigned short* __restrict__ h, float inv_n, size_t total) {
    __shared__ float ssL[512];
    {
        int f = threadIdx.x;
        float mean = stats[f] * inv_n;
        float var = stats[256 + f] * inv_n - mean * mean;
        float sc = bng[f] * rsqrtf(var + 1e-5f);
        ssL[f] = sc;
        ssL[256 + f] = bnb[f] - mean * sc;
    }
    __syncthreads();
    size_t i = ((size_t)blockIdx.x * 256 + threadIdx.x) * 4;
    if (i < total) {
        float a0, a1, a2, a3;
        unpack4(*reinterpret_cast<const uint2*>(agg + i), a0, a1, a2, a3);
        int f = (int)(i & 255);
        float r0 = fmaxf(a0 * ssL[f] + ssL[256 + f], 0.0f);
        float r1 = fmaxf(a1 * ssL[f + 1] + ssL[256 + f + 1], 0.0f);
        float r2 = fmaxf(a2 * ssL[f + 2] + ssL[256 + f + 2], 0.0f);
        float r3 = fmaxf(a3 * ssL[f + 3] + ssL[256 + f + 3], 0.0f);
        *reinterpret_cast<uint2*>(h + i) = pack4(r0, r1, r2, r3);
    }
}

// ---------------- elem_pool: layer-3 BN+ReLU fused directly into global_add_pool ----------------

__global__ __launch_bounds__(256)
void elem_pool_kernel(const unsigned short* __restrict__ agg, const float* __restrict__ stats,
                      const float* __restrict__ bng, const float* __restrict__ bnb,
                      const int* __restrict__ batch, float* __restrict__ g,
                      float inv_n, int N) {
    __shared__ float ssL[512];
    __shared__ int sb[32];
    int f = threadIdx.x;
    {
        float mean = stats[f] * inv_n;
        float var = stats[256 + f] * inv_n - mean * mean;
        float sc = bng[f] * rsqrtf(var + 1e-5f);
        ssL[f] = sc;
        ssL[256 + f] = bnb[f] - mean * sc;
    }
    int r0 = blockIdx.x * 32;
    int rows = min(32, N - r0);
    if (f < 32) sb[f] = (r0 + f < N) ? batch[r0 + f] : -1;
    __syncthreads();
    float sc = ssL[f], sh = ssL[256 + f];
    float acc = 0.0f;
    int cur = sb[0];
    for (int t = 0; t < rows; t++) {
        int b = sb[t];
        if (b != cur) {
            atomicAdd(&g[cur * 256 + f], acc);
            acc = 0.0f;
            cur = b;
        }
        float v = bf2f(agg[(size_t)(r0 + t) * 256 + f]);
        acc += fmaxf(v * sc + sh, 0.0f);
    }
    atomicAdd(&g[cur * 256 + f], acc);
}

// ---------------- head MLP: relu(g@w1+b1)@w2+b2 ----------------

__global__ void head_kernel(const float* __restrict__ g, const float* __restrict__ w1,
                            const float* __restrict__ b1, const float* __restrict__ w2,
                            const float* __restrict__ b2, float* __restrict__ out) {
    __shared__ float gr[256];
    __shared__ float z[128];
    int b = blockIdx.x, t = threadIdx.x;
    gr[t] = g[b * 256 + t];
    gr[t + 128] = g[b * 256 + 128 + t];
    __syncthreads();
    float acc = b1[t];
    for (int k = 0; k < 256; k++) acc += gr[k] * w1[k * 128 + t];
    z[t] = fmaxf(acc, 0.0f);
    __syncthreads();
    if (t < 12) {
        float o = b2[t];
        for (int k = 0; k < 128; k++) o += z[k] * w2[k * 12 + t];
        out[b * 12 + t] = o;
    }
}

// ---------------- launch ----------------

extern "C" void kernel_launch(void* const* d_in, const int* in_sizes, int n_in,
                              void* d_out, int out_size, void* d_ws, size_t ws_size,
                              hipStream_t stream) {
    const float* x      = (const float*)d_in[0];
    const int*   ei     = (const int*)d_in[1];
    const int*   batch  = (const int*)d_in[2];
    const float* node_w = (const float*)d_in[3];
    const float* node_b = (const float*)d_in[4];
    const float* conv_w = (const float*)d_in[5];
    const float* bn_g   = (const float*)d_in[7];
    const float* bn_b   = (const float*)d_in[8];
    const float* hw1    = (const float*)d_in[9];
    const float* hb1    = (const float*)d_in[10];
    const float* hw2    = (const float*)d_in[11];
    const float* hb2    = (const float*)d_in[12];
    float* out = (float*)d_out;

    const int N = in_sizes[2];
    const int E = in_sizes[1] / 2;
    const int H = 256;
    const float inv_n = 1.0f / (float)N;

    char* base = (char*)d_ws;
    size_t off = 0;
    auto alloc = [&](size_t bytes) -> void* {
        off = (off + 255) & ~(size_t)255;
        void* p = base + off;
        off += bytes;
        return p;
    };
    unsigned short* xs  = (unsigned short*)alloc((size_t)(N + 1) * 64 * 2);   // +1 zero row
    unsigned short* y96 = (unsigned short*)alloc((size_t)N * 96 * 2);
    unsigned short* w96 = (unsigned short*)alloc((size_t)256 * 96 * 2);
    unsigned short* h   = (unsigned short*)alloc((size_t)N * H * 2);
    unsigned char*  hws8 = (unsigned char*)alloc((size_t)(N + 1) * H);        // +1 zero row
    unsigned short* agg = (unsigned short*)alloc((size_t)N * H * 2);
    unsigned short* cwT = (unsigned short*)alloc((size_t)3 * H * H * 2);
    // contiguous zero region: cnt | sdis | stats | gpool
    int* zero_region = (int*)alloc(((size_t)2 * N + 512 + 64 * H) * 4);
    int* cnt      = zero_region;
    float* sdis   = (float*)(zero_region + N);
    float* stats  = (float*)(zero_region + 2 * N);
    float* gpool  = (float*)(zero_region + 2 * N + 512);
    int* rowstart = (int*)alloc((size_t)(N + 1) * 4);
    int* scanbuf  = (int*)alloc((size_t)N * 4);
    int* bsum     = (int*)alloc(1024);
    int* boff     = (int*)alloc(1024);
    int* eidx     = (int*)alloc((size_t)(E + 64) * 4);
    float* dis    = (float*)alloc((size_t)N * 4);

    const int* row = ei;
    const int* col = ei + E;

    hipMemsetAsync(zero_region, 0, ((size_t)2 * N + 512 + 64 * H) * 4, stream);

    // cwT transpose + zero pad rows + w96 fuse, one packed grid
    prep_kernel<<<dim3(768 + 1 + 256), 256, 0, stream>>>(
        conv_w, cwT, hws8 + (size_t)N * H, xs + (size_t)N * 64, node_w, node_b, w96);

    deg_kernel<<<dim3((E + 255) / 256), 256, 0, stream>>>(col, cnt, E);
    int nb = (N + 511) / 512;
    scan1_kernel<<<dim3(nb), 512, 0, stream>>>(cnt, scanbuf, bsum, dis, N);
    scan2_kernel<<<dim3(1), 128, 0, stream>>>(bsum, boff, nb);
    scan3_kernel<<<dim3((N + 255) / 256), 256, 0, stream>>>(scanbuf, boff, rowstart, N);
    scatter_kernel<<<dim3((E + 255) / 256), 256, 0, stream>>>(row, col, rowstart, cnt, eidx,
                                                              dis, sdis, E);
    xs_kernel<<<dim3((N * 64 / 4 + 255) / 256), 256, 0, stream>>>(x, dis, xs, N * 64 / 4);

    dim3 gg((N + 127) / 128, H / 128);
    size_t elem_blocks = ((size_t)N * H / 4 + 255) / 256;

    // layer 1: aggregate xs -> y96; K=96 GEMM with fused BN-stats accumulation
    aggx_kernel<<<dim3((N + 15) / 16), 256, 0, stream>>>(xs, rowstart, eidx, dis, sdis, y96, N);
    gemm_bt_kernel<<<gg, 256, 0, stream>>>(y96, w96, agg, nullptr, nullptr, stats, nullptr,
                                           N, 96, H);
    elem_kernel<<<dim3((int)elem_blocks), 256, 0, stream>>>(agg, stats, bn_g, bn_b, h,
                                                            inv_n, (size_t)N * H);

    // layer 2 (fp8 gather)
    gemm_bt_kernel<<<gg, 256, 0, stream>>>(h, cwT + (size_t)1 * H * H, nullptr, hws8, dis,
                                           nullptr, stats, N, H, H);
    agg8_kernel<<<dim3((N + 15) / 16), 256, 0, stream>>>(hws8, rowstart, eidx, dis, agg, stats, N);
    elem_kernel<<<dim3((int)elem_blocks), 256, 0, stream>>>(agg, stats, bn_g + H, bn_b + H, h,
                                                            inv_n, (size_t)N * H);

    // layer 3 (fp8 gather; elem fused into pool)
    gemm_bt_kernel<<<gg, 256, 0, stream>>>(h, cwT + (size_t)2 * H * H, nullptr, hws8, dis,
                                           nullptr, stats, N, H, H);
    agg8_kernel<<<dim3((N + 15) / 16), 256, 0, stream>>>(hws8, rowstart, eidx, dis, agg, stats, N);
    elem_pool_kernel<<<dim3((N + 31) / 32), 256, 0, stream>>>(agg, stats, bn_g + 2 * H,
                                                              bn_b + 2 * H, batch, gpool,
                                                              inv_n, N);

    head_kernel<<<dim3(64), 128, 0, stream>>>(gpool, hw1, hb1, hw2, hb2, out);
}